// Round 4
// baseline (73.867 us; speedup 1.0000x reference)
//
#include <hip/hip_runtime.h>
#include <cstdint>

// Problem constants (from reference)
#define B 64
#define P 5000
#define G 300
#define C 20
#define SCALE_F 512.0f
#define IOU_TH 0.5f
#define NSPLIT 8                              // pred chunks per image (best measured geometry)
#define PCHUNK ((P + NSPLIT - 1) / NSPLIT)    // 625
#define NTA 512
#define NWAVE (NTA / 64)                      // 8 waves per block
#define SPT ((PCHUNK + NTA - 1) / NTA)        // 2 slots per thread
#define NPCH (SPT * NWAVE)                    // 16 pred wave-chunks
#define NCHUNK ((G + 63) / 64)                // 5 target wave-chunks
#define SENT 0x7FFFFFFF

// Match numpy float32 semantics exactly: no FMA contraction (hipcc defaults
// to contract=fast). Division stays IEEE (no fast-math).
#pragma clang fp contract(off)

// ---------------------------------------------------------------------------
// Kernel A: grid (NSPLIT, B) = 512 blocks x 512 threads, 2 blocks/CU
// (16 waves/CU). Round-4 data-path rework, geometry unchanged:
//  * whole 15KB pred chunk staged in LDS by a coalesced dword copy; the
//    class-sorted match phase reads ONLY LDS (round-3's scattered global
//    float2 loads were ~64 L1 line-touches per wave instruction).
//  * ALL histogram/scatter LDS atomics replaced by per-wave ballot counts:
//    lane cc of wave w writes chist[w][cc]/phist[chunk][cc] = popcount of
//    the ballot mask -> race-free full overwrite, no init phase, no atomic
//    serialization. Ballot masks + label boxes are kept in registers from
//    phase 1 to the scatter phase (no re-loads, no re-ballots).
//  * the two serial 20-iter class scans -> two concurrent 20-lane shfl_up
//    wave scans (waves 0 and 1).
//  * barriers: 4 compute barriers + final dump (was 6).
// Invariants: target order within a class = chunk-major then lane order =
// original index order (stable -> preserves jnp.argmax first-occurrence
// tie-break); bucket-restricted strict-> argmax == reference argmax;
// "first eligible claimant (lowest p) per target wins" == the scan;
// IoU arithmetic is op-for-op identical (contract off, IEEE div).
// ---------------------------------------------------------------------------
__global__ __launch_bounds__(NTA, 4) void match_kernel(
    const float* __restrict__ preds,      // [B,P,6]
    const float* __restrict__ labels,     // [B,G,5]
    int* __restrict__ blockfp,            // [B,NSPLIT,G]
    float* __restrict__ out_stats,        // [B,P,3]
    float* __restrict__ out_tcls)         // [B,G]
{
    const int s = blockIdx.x;
    const int b = blockIdx.y;
    const int tid = threadIdx.x;
    const int lane = tid & 63;
    const int w = tid >> 6;

    __shared__ float  plds[PCHUNK * 6];   // staged pred chunk (15 KB)
    __shared__ float4 sb[G];              // class-sorted scaled target boxes
    __shared__ float  sa[G];              // areas
    __shared__ short  ssi[G];             // sorted pos -> original target idx
    __shared__ int    chist[NCHUNK][C];   // per-wave-chunk target class counts
    __shared__ int    phist[NPCH][C];     // per-wave-chunk pred class counts
    __shared__ int    so[C + 1];          // target bucket offsets
    __shared__ int    firstp[G];          // chunk-local lowest claimant
    __shared__ unsigned short psorted[PCHUNK]; // sorted slot -> local pred idx

    const float* lab = labels + (size_t)b * G * 5;
    const float* prd = preds + (size_t)b * P * 6;
    const int pbase = s * PCHUNK;
    const int pend = (pbase + PCHUNK < P) ? pbase + PCHUNK : P;
    const int npred = pend - pbase;       // 625 for all chunks here

    // ---- phase 1: loads + ballot histograms + coalesced stats store ----
    if (tid < G) firstp[tid] = SENT;

    // targets: load box into registers, ballot-count classes (waves 0..4)
    float tx1 = 0, ty1 = 0, tx2 = 0, ty2 = 0;
    int tc = -1;
    unsigned long long tmask = 0;
    if (tid < NCHUNK * 64) {              // waves 0..4 fully active for ballot
        if (tid < G) {
            tx1 = lab[tid * 5 + 0];
            ty1 = lab[tid * 5 + 1];
            tx2 = lab[tid * 5 + 2];
            ty2 = lab[tid * 5 + 3];
            float cf = lab[tid * 5 + 4];
            tc = (int)cf;
            if (s == 0) out_tcls[(size_t)b * G + tid] = cf;
        }
        #pragma unroll
        for (int cc = 0; cc < C; ++cc) {
            unsigned long long m = __ballot(tc == cc);
            if (tc == cc) tmask = m;                       // keep for scatter
            if (lane == cc) chist[w][cc] = __popcll(m);    // race-free write
        }
    }

    // preds: coalesced dword copy of the whole chunk into LDS
    for (int i = tid; i < npred * 6; i += NTA)
        plds[i] = prd[(size_t)pbase * 6 + i];

    // preds: class (L1-hot float2) + dense stats store + ballot histogram
    int myc[SPT];
    unsigned long long pmask[SPT];
    #pragma unroll
    for (int k = 0; k < SPT; ++k) {
        myc[k] = -1;
        pmask[k] = 0;
        int p = pbase + k * NTA + tid;
        if (p < pend) {
            float2 sc = *reinterpret_cast<const float2*>(prd + (size_t)p * 6 + 4);
            myc[k] = (int)sc.y;
            size_t ip3 = ((size_t)b * P + p) * 3;
            out_stats[ip3 + 0] = 0.0f;     // winners flipped to 1.0 by resolve
            out_stats[ip3 + 1] = sc.x;
            out_stats[ip3 + 2] = sc.y;
        }
        #pragma unroll
        for (int cc = 0; cc < C; ++cc) {   // ALL waves execute (full rows)
            unsigned long long m = __ballot(myc[k] == cc);
            if (myc[k] == cc) pmask[k] = m;
            if (lane == cc) phist[k * NWAVE + w][cc] = __popcll(m);
        }
    }
    __syncthreads();

    // ---- phase 2: concurrent wave scans (wave 0: targets, wave 1: preds) ----
    if (tid < 64) {
        int run = 0;
        if (lane < C) {
            #pragma unroll
            for (int u = 0; u < NCHUNK; ++u) {
                int t = chist[u][lane]; chist[u][lane] = run; run += t;
            }
        }
        int v = (lane < C) ? run : 0;      // inclusive scan over class lanes
        #pragma unroll
        for (int d = 1; d < 32; d <<= 1) {
            int o = __shfl_up(v, d);
            if (lane >= d) v += o;
        }
        if (lane < C) so[lane + 1] = v;
        if (lane == 0) so[0] = 0;
    } else if (tid < 128) {
        int run = 0;
        if (lane < C) {
            #pragma unroll
            for (int u = 0; u < NPCH; ++u) {
                int t = phist[u][lane]; phist[u][lane] = run; run += t;
            }
        }
        int v = (lane < C) ? run : 0;
        #pragma unroll
        for (int d = 1; d < 32; d <<= 1) {
            int o = __shfl_up(v, d);
            if (lane >= d) v += o;
        }
        int excl = v - run;                // class base among preds
        if (lane < C) {
            #pragma unroll
            for (int u = 0; u < NPCH; ++u) phist[u][lane] += excl;
        }
    }
    __syncthreads();

    // ---- phase 3: scatters (registers + ballot ranks, no atomics) ----
    if (tid < G) {
        int rank = chist[w][tc] + __popcll(tmask & ((1ull << lane) - 1));
        int pos = so[tc] + rank;           // stable: chunk-major + lane order
        float x1 = tx1 * SCALE_F;          // *512 exact (pow2)
        float y1 = ty1 * SCALE_F;
        float x2 = tx2 * SCALE_F;
        float y2 = ty2 * SCALE_F;
        sb[pos] = make_float4(x1, y1, x2, y2);
        sa[pos] = (x2 - x1) * (y2 - y1);
        ssi[pos] = (short)tid;
    }
    #pragma unroll
    for (int k = 0; k < SPT; ++k) {
        if (myc[k] >= 0) {
            int pos = phist[k * NWAVE + w][myc[k]]
                    + __popcll(pmask[k] & ((1ull << lane) - 1));
            psorted[pos] = (unsigned short)(k * NTA + tid);  // local pred idx
        }
    }
    __syncthreads();

    // ---- phase 4: match (slot-ordered, LDS-only data path) ----
    #pragma unroll
    for (int k = 0; k < SPT; ++k) {
        int slot = k * NTA + tid;
        if (slot >= npred) continue;
        int li = psorted[slot];
        const float* pp = &plds[li * 6];
        float2 q0 = *reinterpret_cast<const float2*>(pp);       // x1,y1
        float2 q1 = *reinterpret_cast<const float2*>(pp + 2);   // x2,y2
        float2 q2 = *reinterpret_cast<const float2*>(pp + 4);   // score,cls
        float px1 = q0.x * SCALE_F;
        float py1 = q0.y * SCALE_F;
        float px2 = q1.x * SCALE_F;
        float py2 = q1.y * SCALE_F;
        float score = q2.x;
        int c = (int)q2.y;
        float parea = (px2 - px1) * (py2 - py1);

        int lo = so[c], hi = so[c + 1];
        float best = -1.0f;
        int bi = -1;
        // bucket preserves original order; strict > keeps FIRST max occurrence
        for (int j = lo; j < hi; ++j) {
            float4 tb = sb[j];                 // few distinct j per wave
            float lx = fmaxf(px1, tb.x);
            float ly = fmaxf(py1, tb.y);
            float rx = fminf(px2, tb.z);
            float ry = fminf(py2, tb.w);
            float wd = fmaxf(rx - lx, 0.0f);
            float ht = fmaxf(ry - ly, 0.0f);
            float inter = wd * ht;
            float uni = (parea + sa[j]) - inter;   // reference assoc order
            float iou = inter / uni;               // IEEE div
            if (iou > best) { best = iou; bi = ssi[j]; }
        }

        bool eligible = (score > 0.0f) && (hi > lo) && (best > IOU_TH);
        if (eligible) atomicMin(&firstp[bi], pbase + li);
    }
    __syncthreads();

    // ---- phase 5: dump chunk-local claims (coalesced) ----
    if (tid < G)
        blockfp[((size_t)b * NSPLIT + s) * G + tid] = firstp[tid];
}

// ---------------------------------------------------------------------------
// Kernel B: tiny sparse resolve. One block per image; thread t min-reduces
// the NSPLIT chunk-local claims for target t; if a winner exists, that pred
// gets corr=1.0 (one 4B store; <=300 per image). lf[t]=p implies p claimed t
// (p claims only its own argmax), so no index array is needed. A pred wins at
// most one target, so the sparse stores never collide. Kernel boundary
// guarantees visibility/ordering of kernel A's stores.
// ---------------------------------------------------------------------------
__global__ __launch_bounds__(512) void resolve_kernel(
    const int* __restrict__ blockfp,      // [B,NSPLIT,G]
    float* __restrict__ out_stats)        // [B,P,3]
{
    const int b = blockIdx.x;
    const int t = threadIdx.x;
    if (t >= G) return;

    const int* fp = blockfp + (size_t)b * NSPLIT * G + t;
    int m = fp[0];
    #pragma unroll
    for (int s = 1; s < NSPLIT; ++s) m = min(m, fp[s * G]);

    if (m != SENT)
        out_stats[((size_t)b * P + m) * 3] = 1.0f;
}

extern "C" void kernel_launch(void* const* d_in, const int* in_sizes, int n_in,
                              void* d_out, int out_size, void* d_ws, size_t ws_size,
                              hipStream_t stream) {
    const float* output = (const float*)d_in[0];   // [B,P,6]
    const float* labels = (const float*)d_in[1];   // [B,G,5]

    float* out_stats = (float*)d_out;                       // [B,P,3]
    float* out_tcls  = (float*)d_out + (size_t)B * P * 3;   // [B,G]

    // workspace layout (no init required — kernel A writes every slot)
    int* blockfp = (int*)d_ws;                              // B*NSPLIT*G ints

    dim3 grid(NSPLIT, B);
    match_kernel<<<grid, NTA, 0, stream>>>(output, labels, blockfp,
                                           out_stats, out_tcls);
    resolve_kernel<<<dim3(B), 512, 0, stream>>>(blockfp, out_stats);
}